// Round 9
// baseline (28.034 us; speedup 1.0000x reference)
//
#include <hip/hip_runtime.h>
#include <hip/hip_bf16.h>
#include <hip/hip_fp8.h>
#include <stdint.h>

// Problem constants (fixed by reference): B=2048, D=256, Vg=2, Vt=4 (only j<2 used), T=0.2
#define TB 2048
#define TD 256

typedef long long                                         fp8x8;   // 8 fp8 = 2 VGPR
typedef __attribute__((ext_vector_type(16))) float        f32x16;

#define SQRT5 2.23606797749979f   // fold sqrt(1/T)=sqrt(5) into BOTH normalized operands

// ---------------------------------------------------------------------------
// Kernel 1: normalize rows, scale by sqrt(5), cast fp8-e4m3 (OCP), write in
// MFMA fragment order: pq2[v][grp][g][col] of 8B granules (granule g holds
// k in [8g,8g+8) for batch-col `col`). v in {p_i0,p_i1,q_j0,q_j1}.
// float4 global loads (16B/lane), 32x32-row transpose through LDS.
// ---------------------------------------------------------------------------
__global__ __launch_bounds__(256) void nnclr_prep(const float* __restrict__ proj,
                                                  const float* __restrict__ pred,
                                                  unsigned char* __restrict__ pq2) {
    const int grp = blockIdx.x;      // 0..63
    const int v   = blockIdx.y;      // 0..3
    const int t   = threadIdx.x;     // 0..255

    __shared__ float rowbuf[32][260];   // stride 260: 16B-aligned rows, <=2-way conflicts
    __shared__ float scales[32];

    // phase 1: 8 float4 loads per thread, write-through to LDS
    #pragma unroll
    for (int it = 0; it < 8; ++it) {
        const int f = it * 256 + t;       // 0..2047 float4-slot
        const int m = f >> 6, q = f & 63; // row, float4-col
        const int b = grp * 32 + m;
        const float4* src = (v < 2) ? (const float4*)(proj + ((size_t)b * 2 + v) * TD)
                                    : (const float4*)(pred + ((size_t)b * 4 + (v - 2)) * TD);
        const float4 val = src[q];
        *(float4*)&rowbuf[m][q * 4] = val;
    }
    __syncthreads();

    // norms: 8 threads per row
    {
        const int row = t >> 3, l8 = t & 7;
        float ss = 0.f;
        #pragma unroll
        for (int n = 0; n < 32; ++n) { const float y = rowbuf[row][l8 + 8 * n]; ss += y * y; }
        ss += __shfl_xor(ss, 1, 64);
        ss += __shfl_xor(ss, 2, 64);
        ss += __shfl_xor(ss, 4, 64);
        if (l8 == 0) scales[row] = SQRT5 / fmaxf(sqrtf(ss), 1e-12f);
    }
    __syncthreads();

    // phase 2: pack 4 fp8/thread/iter, coalesced uint stores.
    // byte addr within (v,grp) tile: (g*32 + col)*8 + e ; here g==m, e = 4*e4+i.
    unsigned int* dst32 = (unsigned int*)(pq2 + (size_t)(v * 64 + grp) * 8192);
    #pragma unroll
    for (int it = 0; it < 8; ++it) {
        const int u   = it * 256 + t;     // uint index, 0..2047
        const int m   = u >> 6;
        const int col = (u >> 1) & 31;
        const int e4  = u & 1;
        const float sc = scales[col];
        unsigned int w = 0;
        #pragma unroll
        for (int i = 0; i < 4; ++i) {
            const float y = rowbuf[col][m * 8 + 4 * e4 + i] * sc;
            const __hip_fp8_e4m3 f8(y);
            w |= ((unsigned int)f8.__x) << (8 * i);
        }
        dst32[u] = w;
    }
}

// ---------------------------------------------------------------------------
// Kernel 2: fp8 MFMA, no staging LDS, no main-loop barriers. Block (rb,ch,j):
// rows b0..b0+31 x cols [ch*512,+512) for BOTH i (B-frag reused 2x). A/B frags
// direct from L2-resident pq2 (512B/wave-load). 8-deep rolling B prefetch.
// Fixed-max m=5 sum-of-exp epilogue. ~165 VGPR -> no spill, 8 waves/CU.
// ---------------------------------------------------------------------------
__global__ __launch_bounds__(256, 2) void nnclr_main(const unsigned char* __restrict__ pq2,
                                                     float* __restrict__ sPart,  // [4][2048][4]
                                                     float* __restrict__ dPart)  // [4][2048][4]
{
    const int rb = blockIdx.x, ch = blockIdx.y, j = blockIdx.z;
    const int tid = threadIdx.x, lane = tid & 63, wave = tid >> 6;
    const int cl = lane & 31, hk = lane >> 5;
    const int b0 = rb * 32;

    const fp8x8* P = (const fp8x8*)pq2;                 // granule-indexed (8B)
    // A granule: ((i*64 + rb)*32 + g)*32 + cl , g = 2*ks + hk
    fp8x8 aF0[16], aF1[16];
    #pragma unroll
    for (int ks = 0; ks < 16; ++ks) {
        const int g = 2 * ks + hk;
        aF0[ks] = P[((0 * 64 + rb) * 32 + g) * 32 + cl];
        aF1[ks] = P[((1 * 64 + rb) * 32 + g) * 32 + cl];
    }

    float sAcc0[16], sAcc1[16];
    #pragma unroll
    for (int r = 0; r < 16; ++r) { sAcc0[r] = 0.f; sAcc1[r] = 0.f; }
    float d0 = 0.f, d1 = 0.f;
    // lane's diagonal slot: holds C[row=cl][col=cl] iff hk==(cl>>2)&1, at r=rDiag
    const int  rDiag    = (cl & 3) + 4 * (cl >> 3);
    const bool laneDiag = (((cl >> 2) & 1) == hk);

    const fp8x8* Bbase = P + (size_t)(2 + j) * 64 * 32 * 32;
    const int cg0 = ch * 16 + wave * 4;                 // this wave's first col-group

    // 8-deep rolling prefetch of the flat 64-granule B stream
    fp8x8 bq[8];
    #pragma unroll
    for (int k = 0; k < 8; ++k) bq[k] = Bbase[(cg0 * 32 + 2 * k + hk) * 32 + cl];

    #pragma unroll
    for (int cgl = 0; cgl < 4; ++cgl) {
        const int cg = cg0 + cgl;
        f32x16 acc0, acc1;
        #pragma unroll
        for (int r = 0; r < 16; ++r) { acc0[r] = 0.f; acc1[r] = 0.f; }
        #pragma unroll
        for (int ks = 0; ks < 16; ++ks) {
            const fp8x8 b = bq[ks & 7];
            if (ks < 8)        bq[ks & 7] = Bbase[(cg * 32 + 2 * (ks + 8) + hk) * 32 + cl];
            else if (cgl < 3)  bq[ks & 7] = Bbase[((cg + 1) * 32 + 2 * (ks - 8) + hk) * 32 + cl];
            acc0 = __builtin_amdgcn_mfma_f32_32x32x16_fp8_fp8(aF0[ks], b, acc0, 0, 0, 0);
            acc1 = __builtin_amdgcn_mfma_f32_32x32x16_fp8_fp8(aF1[ks], b, acc1, 0, 0, 0);
        }
        // epilogue: fixed-max sum-of-exp + diag pick (static vector indexing)
        const bool diagCG = (cg == rb);                 // wave-uniform
        #pragma unroll
        for (int r = 0; r < 16; ++r) {
            const float v0 = acc0[r], v1 = acc1[r];
            sAcc0[r] += __expf(v0 - 5.0f);
            sAcc1[r] += __expf(v1 - 5.0f);
            if (diagCG) {
                const bool m = laneDiag && (r == rDiag);
                d0 += m ? v0 : 0.f;
                d1 += m ? v1 : 0.f;
            }
        }
    }

    // per-row col-sum: reduce over the 32 lanes of each hk half
    #pragma unroll
    for (int r = 0; r < 16; ++r) {
        float s0 = sAcc0[r], s1 = sAcc1[r];
        #pragma unroll
        for (int msk = 1; msk < 32; msk <<= 1) {
            s0 += __shfl_xor(s0, msk, 64);
            s1 += __shfl_xor(s1, msk, 64);
        }
        sAcc0[r] = s0; sAcc1[r] = s1;
    }

    __shared__ float sArr[2][4][32];
    __shared__ float dArr[2][4][32];
    if (cl == 0) {
        #pragma unroll
        for (int r = 0; r < 16; ++r) {
            const int rowl = (r & 3) + 8 * (r >> 2) + 4 * hk;
            sArr[0][wave][rowl] = sAcc0[r];
            sArr[1][wave][rowl] = sAcc1[r];
        }
    }
    if (laneDiag) { dArr[0][wave][cl] = d0; dArr[1][wave][cl] = d1; }
    __syncthreads();
    if (tid < 64) {
        const int i = tid >> 5, row = tid & 31;
        float s = 0.f, d = 0.f;
        #pragma unroll
        for (int w = 0; w < 4; ++w) { s += sArr[i][w][row]; d += dArr[i][w][row]; }
        const int pair = i * 2 + j;
        const int b = b0 + row;
        sPart[((size_t)pair * TB + b) * 4 + ch] = s;
        dPart[((size_t)pair * TB + b) * 4 + ch] = d;
    }
}

// ---------------------------------------------------------------------------
// Kernel 3 (merged): 1 block x 1024 thr. Per (pair,row): combine 4 chunks,
// L = 5 + ln(s) - d; block-reduce per pair; thread 0 -> 3 outputs.
// 256 KB coalesced float4 reads, 16 float4s in flight per thread.
// ---------------------------------------------------------------------------
__global__ __launch_bounds__(1024) void nnclr_final(const float* __restrict__ sPart,
                                                    const float* __restrict__ dPart,
                                                    float* __restrict__ out) {
    const int tid = threadIdx.x;
    float acc[4] = {0.f, 0.f, 0.f, 0.f};
    #pragma unroll
    for (int k = 0; k < 8; ++k) {
        const int item = k * 1024 + tid;                // pair*2048 + row ; pair = k>>1
        const float4 sv = ((const float4*)sPart)[item];
        const float4 dv = ((const float4*)dPart)[item];
        const float s = (sv.x + sv.y) + (sv.z + sv.w);
        const float d = (dv.x + dv.y) + (dv.z + dv.w);
        acc[k >> 1] += 5.0f + logf(s) - d;
    }
    __shared__ float red[16][4];
    const int lane = tid & 63, wave = tid >> 6;
    #pragma unroll
    for (int p = 0; p < 4; ++p) {
        #pragma unroll
        for (int m = 1; m < 64; m <<= 1) acc[p] += __shfl_xor(acc[p], m, 64);
    }
    if (lane == 0) {
        #pragma unroll
        for (int p = 0; p < 4; ++p) red[wave][p] = acc[p];
    }
    __syncthreads();
    if (tid == 0) {
        float L[4];
        #pragma unroll
        for (int p = 0; p < 4; ++p) {
            float a = 0.f;
            for (int w = 0; w < 16; ++w) a += red[w][p];
            L[p] = a / (float)TB;         // mean over b
        }
        const float gs = L[1] + L[2];                 // L[0][1] + L[1][0]
        const float ls = L[0] + L[1] + L[2] + L[3];   // all four (Vl==Vg==2)
        out[0] = (gs + ls) / 6.0f;        // total
        out[1] = gs * 0.5f;               // global_loss
        out[2] = ls * 0.25f;              // local_loss
    }
}

extern "C" void kernel_launch(void* const* d_in, const int* in_sizes, int n_in,
                              void* d_out, int out_size, void* d_ws, size_t ws_size,
                              hipStream_t stream) {
    const float* projected = (const float*)d_in[0];   // [2048][2][256] f32
    const float* predicted = (const float*)d_in[1];   // [2048][4][256] f32

    unsigned char* pq2 = (unsigned char*)d_ws;                          // 2 MB fp8, fragment-ordered
    float* sPart = (float*)((char*)d_ws + 4u * 1024u * 1024u);          // 128 KB
    float* dPart = sPart + (size_t)4 * TB * 4;                          // 128 KB
    float* out = (float*)d_out;

    dim3 gprep(64, 4);
    nnclr_prep<<<gprep, 256, 0, stream>>>(projected, predicted, pq2);
    dim3 gmain(64, 4, 2);
    nnclr_main<<<gmain, 256, 0, stream>>>(pq2, sPart, dPart);
    nnclr_final<<<1, 1024, 0, stream>>>(sPart, dPart, out);
}

// Round 10
// 26.451 us; speedup vs baseline: 1.0598x; 1.0598x over previous
//
#include <hip/hip_runtime.h>
#include <hip/hip_bf16.h>
#include <hip/hip_fp8.h>
#include <stdint.h>

// Problem constants (fixed by reference): B=2048, D=256, Vg=2, Vt=4 (only j<2 used), T=0.2
#define TB 2048
#define TD 256

typedef long long                                         fp8x8;   // 8 fp8 = 2 VGPR
typedef __attribute__((ext_vector_type(8)))  int          int8v;   // 32 fp8 = 8 VGPR
typedef __attribute__((ext_vector_type(16))) float        f32x16;

union frag32 { fp8x8 g[4]; int8v v; };   // 4 x 8B granules = one 32x32x64 operand

#define SQRT5 2.23606797749979f   // fold sqrt(1/T)=sqrt(5) into BOTH normalized operands
#define SCALE1 0x7F               // E8M0: 2^(127-127) = 1.0

// ---------------------------------------------------------------------------
// Kernel 1: normalize rows, scale by sqrt(5), cast fp8-e4m3 (OCP), write in
// MFMA fragment order: pq2[v][grp][g][col] of 8B granules (granule g holds
// k in [8g,8g+8) for batch-col `col`). v in {p_i0,p_i1,q_j0,q_j1}.
// float4 global loads (16B/lane), 32x32-row transpose through LDS.
// ---------------------------------------------------------------------------
__global__ __launch_bounds__(256) void nnclr_prep(const float* __restrict__ proj,
                                                  const float* __restrict__ pred,
                                                  unsigned char* __restrict__ pq2) {
    const int grp = blockIdx.x;      // 0..63
    const int v   = blockIdx.y;      // 0..3
    const int t   = threadIdx.x;     // 0..255

    __shared__ float rowbuf[32][260];   // stride 260: 16B-aligned rows, <=2-way conflicts
    __shared__ float scales[32];

    // phase 1: 8 float4 loads per thread, write-through to LDS
    #pragma unroll
    for (int it = 0; it < 8; ++it) {
        const int f = it * 256 + t;       // 0..2047 float4-slot
        const int m = f >> 6, q = f & 63; // row, float4-col
        const int b = grp * 32 + m;
        const float4* src = (v < 2) ? (const float4*)(proj + ((size_t)b * 2 + v) * TD)
                                    : (const float4*)(pred + ((size_t)b * 4 + (v - 2)) * TD);
        const float4 val = src[q];
        *(float4*)&rowbuf[m][q * 4] = val;
    }
    __syncthreads();

    // norms: 8 threads per row
    {
        const int row = t >> 3, l8 = t & 7;
        float ss = 0.f;
        #pragma unroll
        for (int n = 0; n < 32; ++n) { const float y = rowbuf[row][l8 + 8 * n]; ss += y * y; }
        ss += __shfl_xor(ss, 1, 64);
        ss += __shfl_xor(ss, 2, 64);
        ss += __shfl_xor(ss, 4, 64);
        if (l8 == 0) scales[row] = SQRT5 / fmaxf(sqrtf(ss), 1e-12f);
    }
    __syncthreads();

    // phase 2: pack 4 fp8/thread/iter, coalesced uint stores.
    // byte addr within (v,grp) tile: (g*32 + col)*8 + e ; here g==m, e = 4*e4+i.
    unsigned int* dst32 = (unsigned int*)(pq2 + (size_t)(v * 64 + grp) * 8192);
    #pragma unroll
    for (int it = 0; it < 8; ++it) {
        const int u   = it * 256 + t;     // uint index, 0..2047
        const int m   = u >> 6;
        const int col = (u >> 1) & 31;
        const int e4  = u & 1;
        const float sc = scales[col];
        unsigned int w = 0;
        #pragma unroll
        for (int i = 0; i < 4; ++i) {
            const float y = rowbuf[col][m * 8 + 4 * e4 + i] * sc;
            const __hip_fp8_e4m3 f8(y);
            w |= ((unsigned int)f8.__x) << (8 * i);
        }
        dst32[u] = w;
    }
}

// ---------------------------------------------------------------------------
// Kernel 2: MX-scaled fp8 MFMA (32x32x64, scales=1.0, 2.14x non-scaled rate).
// Block (rb,ch,j): rows b0..b0+31 x cols [ch*512,+512) for BOTH i. A/B frags
// direct from L2-resident pq2. 32x32x64 operand = granules 8*kb+4*hk+{0..3}
// (lane k-range [32*hk,+32) per kb). Double-buffered B frag sets.
// Fixed-max m=5 sum-of-exp epilogue. ~212 VGPR -> 2 blocks/CU.
// ---------------------------------------------------------------------------
__global__ __launch_bounds__(256, 2) void nnclr_main(const unsigned char* __restrict__ pq2,
                                                     float* __restrict__ sPart,  // [4][2048][4]
                                                     float* __restrict__ dPart)  // [4][2048][4]
{
    const int rb = blockIdx.x, ch = blockIdx.y, j = blockIdx.z;
    const int tid = threadIdx.x, lane = tid & 63, wave = tid >> 6;
    const int cl = lane & 31, hk = lane >> 5;
    const int b0 = rb * 32;

    const fp8x8* P = (const fp8x8*)pq2;                 // granule-indexed (8B)
    // A fragments: aF{i}[kb], kb = K/64 block
    frag32 aF0[4], aF1[4];
    #pragma unroll
    for (int kb = 0; kb < 4; ++kb) {
        #pragma unroll
        for (int q = 0; q < 4; ++q) {
            const int g = 8 * kb + 4 * hk + q;
            aF0[kb].g[q] = P[((0 * 64 + rb) * 32 + g) * 32 + cl];
            aF1[kb].g[q] = P[((1 * 64 + rb) * 32 + g) * 32 + cl];
        }
    }

    float sAcc0[16], sAcc1[16];
    #pragma unroll
    for (int r = 0; r < 16; ++r) { sAcc0[r] = 0.f; sAcc1[r] = 0.f; }
    float d0 = 0.f, d1 = 0.f;
    // lane's diagonal slot: holds C[row=cl][col=cl] iff hk==(cl>>2)&1, at r=rDiag
    const int  rDiag    = (cl & 3) + 4 * (cl >> 3);
    const bool laneDiag = (((cl >> 2) & 1) == hk);

    const fp8x8* Bbase = P + (size_t)(2 + j) * 64 * 32 * 32;
    const int cg0 = ch * 16 + wave * 4;                 // this wave's first col-group

    // double-buffered B fragment sets (all indices static after full unroll)
    frag32 bf[2][4];
    #pragma unroll
    for (int kb = 0; kb < 4; ++kb)
        #pragma unroll
        for (int q = 0; q < 4; ++q)
            bf[0][kb].g[q] = Bbase[((size_t)cg0 * 32 + 8 * kb + 4 * hk + q) * 32 + cl];

    #pragma unroll
    for (int cgl = 0; cgl < 4; ++cgl) {
        const int cg = cg0 + cgl;
        if (cgl < 3) {
            #pragma unroll
            for (int kb = 0; kb < 4; ++kb)
                #pragma unroll
                for (int q = 0; q < 4; ++q)
                    bf[(cgl + 1) & 1][kb].g[q] =
                        Bbase[((size_t)(cg + 1) * 32 + 8 * kb + 4 * hk + q) * 32 + cl];
        }
        f32x16 acc0, acc1;
        #pragma unroll
        for (int r = 0; r < 16; ++r) { acc0[r] = 0.f; acc1[r] = 0.f; }
        #pragma unroll
        for (int kb = 0; kb < 4; ++kb) {
            acc0 = __builtin_amdgcn_mfma_scale_f32_32x32x64_f8f6f4(
                       aF0[kb].v, bf[cgl & 1][kb].v, acc0, 0, 0, 0, SCALE1, 0, SCALE1);
            acc1 = __builtin_amdgcn_mfma_scale_f32_32x32x64_f8f6f4(
                       aF1[kb].v, bf[cgl & 1][kb].v, acc1, 0, 0, 0, SCALE1, 0, SCALE1);
        }
        // epilogue: fixed-max sum-of-exp + diag pick (static vector indexing)
        const bool diagCG = (cg == rb);                 // wave-uniform
        #pragma unroll
        for (int r = 0; r < 16; ++r) {
            const float v0 = acc0[r], v1 = acc1[r];
            sAcc0[r] += __expf(v0 - 5.0f);
            sAcc1[r] += __expf(v1 - 5.0f);
            if (diagCG) {
                const bool m = laneDiag && (r == rDiag);
                d0 += m ? v0 : 0.f;
                d1 += m ? v1 : 0.f;
            }
        }
    }

    // per-row col-sum: reduce over the 32 lanes of each hk half
    #pragma unroll
    for (int r = 0; r < 16; ++r) {
        float s0 = sAcc0[r], s1 = sAcc1[r];
        #pragma unroll
        for (int msk = 1; msk < 32; msk <<= 1) {
            s0 += __shfl_xor(s0, msk, 64);
            s1 += __shfl_xor(s1, msk, 64);
        }
        sAcc0[r] = s0; sAcc1[r] = s1;
    }

    __shared__ float sArr[2][4][32];
    __shared__ float dArr[2][4][32];
    if (cl == 0) {
        #pragma unroll
        for (int r = 0; r < 16; ++r) {
            const int rowl = (r & 3) + 8 * (r >> 2) + 4 * hk;
            sArr[0][wave][rowl] = sAcc0[r];
            sArr[1][wave][rowl] = sAcc1[r];
        }
    }
    if (laneDiag) { dArr[0][wave][cl] = d0; dArr[1][wave][cl] = d1; }
    __syncthreads();
    if (tid < 64) {
        const int i = tid >> 5, row = tid & 31;
        float s = 0.f, d = 0.f;
        #pragma unroll
        for (int w = 0; w < 4; ++w) { s += sArr[i][w][row]; d += dArr[i][w][row]; }
        const int pair = i * 2 + j;
        const int b = b0 + row;
        sPart[((size_t)pair * TB + b) * 4 + ch] = s;
        dPart[((size_t)pair * TB + b) * 4 + ch] = d;
    }
}

// ---------------------------------------------------------------------------
// Kernel 3 (merged): 1 block x 1024 thr. Per (pair,row): combine 4 chunks,
// L = 5 + ln(s) - d; block-reduce per pair; thread 0 -> 3 outputs.
// ---------------------------------------------------------------------------
__global__ __launch_bounds__(1024) void nnclr_final(const float* __restrict__ sPart,
                                                    const float* __restrict__ dPart,
                                                    float* __restrict__ out) {
    const int tid = threadIdx.x;
    float acc[4] = {0.f, 0.f, 0.f, 0.f};
    #pragma unroll
    for (int k = 0; k < 8; ++k) {
        const int item = k * 1024 + tid;                // pair*2048 + row ; pair = k>>1
        const float4 sv = ((const float4*)sPart)[item];
        const float4 dv = ((const float4*)dPart)[item];
        const float s = (sv.x + sv.y) + (sv.z + sv.w);
        const float d = (dv.x + dv.y) + (dv.z + dv.w);
        acc[k >> 1] += 5.0f + logf(s) - d;
    }
    __shared__ float red[16][4];
    const int lane = tid & 63, wave = tid >> 6;
    #pragma unroll
    for (int p = 0; p < 4; ++p) {
        #pragma unroll
        for (int m = 1; m < 64; m <<= 1) acc[p] += __shfl_xor(acc[p], m, 64);
    }
    if (lane == 0) {
        #pragma unroll
        for (int p = 0; p < 4; ++p) red[wave][p] = acc[p];
    }
    __syncthreads();
    if (tid == 0) {
        float L[4];
        #pragma unroll
        for (int p = 0; p < 4; ++p) {
            float a = 0.f;
            for (int w = 0; w < 16; ++w) a += red[w][p];
            L[p] = a / (float)TB;         // mean over b
        }
        const float gs = L[1] + L[2];                 // L[0][1] + L[1][0]
        const float ls = L[0] + L[1] + L[2] + L[3];   // all four (Vl==Vg==2)
        out[0] = (gs + ls) / 6.0f;        // total
        out[1] = gs * 0.5f;               // global_loss
        out[2] = ls * 0.25f;              // local_loss
    }
}

extern "C" void kernel_launch(void* const* d_in, const int* in_sizes, int n_in,
                              void* d_out, int out_size, void* d_ws, size_t ws_size,
                              hipStream_t stream) {
    const float* projected = (const float*)d_in[0];   // [2048][2][256] f32
    const float* predicted = (const float*)d_in[1];   // [2048][4][256] f32

    unsigned char* pq2 = (unsigned char*)d_ws;                          // 2 MB fp8, fragment-ordered
    float* sPart = (float*)((char*)d_ws + 4u * 1024u * 1024u);          // 128 KB
    float* dPart = sPart + (size_t)4 * TB * 4;                          // 128 KB
    float* out = (float*)d_out;

    dim3 gprep(64, 4);
    nnclr_prep<<<gprep, 256, 0, stream>>>(projected, predicted, pq2);
    dim3 gmain(64, 4, 2);
    nnclr_main<<<gmain, 256, 0, stream>>>(pq2, sPart, dPart);
    nnclr_final<<<1, 1024, 0, stream>>>(sPart, dPart, out);
}